// Round 1
// baseline (2242.863 us; speedup 1.0000x reference)
//
#include <hip/hip_runtime.h>
#include <cstdint>

#define B_    512
#define T_    64
#define VOCAB_ 10000
#define EMB_  512
#define HID_  1024
#define G4H_  4096      // 4*HID
#define KCAT_ 1536      // EMB + HID
#define NIMG_ 2048

typedef _Float16 half8 __attribute__((ext_vector_type(8)));
typedef float floatx4 __attribute__((ext_vector_type(4)));

// Async global->LDS, 16B per lane. LDS dest must be the wave-uniform base;
// HW adds lane*16. Source address is per-lane (gather OK).
__device__ __forceinline__ void async_copy16(void* lds_uniform, const void* gsrc) {
    __builtin_amdgcn_global_load_lds(
        (__attribute__((address_space(1))) void*)(uintptr_t)gsrc,
        (__attribute__((address_space(3))) void*)(uint32_t)(uintptr_t)lds_uniform,
        16, 0, 0);
}

// ---------------------------------------------------------------------------
// One-time conversions: emb->f16, [W_ih|W_hh]->f16 concat (N x KCAT, B^T
// layout), W_out->f16, bias = b_ih+b_hh, zero-init c (f32) and h (f16).
// ---------------------------------------------------------------------------
__global__ __launch_bounds__(256) void convert_kernel(
    const float* __restrict__ emb, const float* __restrict__ W_ih,
    const float* __restrict__ W_hh, const float* __restrict__ b_ih,
    const float* __restrict__ b_hh, const float* __restrict__ W_out,
    _Float16* __restrict__ emb16, _Float16* __restrict__ Wc16,
    _Float16* __restrict__ Wout16, float* __restrict__ bias,
    float* __restrict__ c, _Float16* __restrict__ h16)
{
    const long long EMB_N = (long long)VOCAB_ * EMB_;   // 5,120,000
    const long long WC_N  = (long long)G4H_ * KCAT_;    // 6,291,456
    const long long WO_N  = (long long)NIMG_ * HID_;    // 2,097,152
    const long long BI_N  = G4H_;
    const long long ST_N  = (long long)B_ * HID_;       // 524,288

    long long i = (long long)blockIdx.x * 256 + threadIdx.x;
    if (i < EMB_N) { emb16[i] = (_Float16)emb[i]; return; }
    i -= EMB_N;
    if (i < WC_N) {
        int n = (int)(i / KCAT_);
        int k = (int)(i % KCAT_);
        float v = (k < EMB_) ? W_ih[(size_t)n * EMB_ + k]
                             : W_hh[(size_t)n * HID_ + (k - EMB_)];
        Wc16[i] = (_Float16)v;
        return;
    }
    i -= WC_N;
    if (i < WO_N) { Wout16[i] = (_Float16)W_out[i]; return; }
    i -= WO_N;
    if (i < BI_N) { bias[i] = b_ih[i] + b_hh[i]; return; }
    i -= BI_N;
    if (i < ST_N) { c[i] = 0.0f; return; }
    i -= ST_N;
    if (i < ST_N) { h16[i] = (_Float16)0.0f; }
}

// ---------------------------------------------------------------------------
// f16 MFMA GEMM, B^T weights: Out[m][n] = bias[n] + sum_k A[m][k]*Bw[n][k]
// Block: 256 thr = 4 waves (2x2), tile 64(M) x 128(N), BK=32.
// GATHER: A row m, k<512 from emb16[tok[m]], k>=512 from h16[m].
// ---------------------------------------------------------------------------
template <bool GATHER>
__global__ __launch_bounds__(256) void gemm_f16(
    const _Float16* __restrict__ A0,  // GATHER: emb16 ; else plain A (stride K)
    const int* __restrict__ tok,      // GATHER: token of row b at tok[b*tokStride]
    int tokStride,
    const _Float16* __restrict__ A1,  // GATHER: h16
    const _Float16* __restrict__ Bw,  // [N][K] row-major (B^T layout)
    const float* __restrict__ bias,   // [N]
    float* __restrict__ Out,          // [M][N] fp32
    int N, int K)
{
    __shared__ __align__(16) _Float16 As[64 * 32];
    __shared__ __align__(16) _Float16 Bs[128 * 32];
    __shared__ int tok_s[64];

    const int tid  = threadIdx.x;
    const int wid  = tid >> 6;
    const int lane = tid & 63;
    const int lcol = lane & 15;   // col of C / m-row of A-frag / n-row of B-frag
    const int quad = lane >> 4;   // 0..3
    const int wm   = wid >> 1;    // wave row 0..1 (32 rows each)
    const int wn   = wid & 1;     // wave col 0..1 (64 cols each)

    const int b0 = blockIdx.x * 64;
    const int n0 = blockIdx.y * 128;

    if (GATHER) {
        if (tid < 64) tok_s[tid] = tok[(size_t)(b0 + tid) * tokStride];
        __syncthreads();
    }

    floatx4 acc[2][4];
#pragma unroll
    for (int i = 0; i < 2; ++i)
#pragma unroll
        for (int j = 0; j < 4; ++j) acc[i][j] = (floatx4){0.f, 0.f, 0.f, 0.f};

    const int ar = tid >> 2;  // staging row 0..63
    const int kq = tid & 3;   // 16B chunk in row (8 halves)

    for (int k0 = 0; k0 < K; k0 += 32) {
        // ---- stage A tile 64x32 (4 KB, one 256-thread shot) ----
        const _Float16* asrc;
        if (GATHER) {
            if (k0 < EMB_) asrc = A0 + (size_t)tok_s[ar] * EMB_ + (k0 + kq * 8);
            else           asrc = A1 + (size_t)(b0 + ar) * HID_ + (k0 - EMB_ + kq * 8);
        } else {
            asrc = A0 + (size_t)(b0 + ar) * K + (k0 + kq * 8);
        }
        async_copy16((char*)As + (wid << 10), asrc);

        // ---- stage B tile 128x32 (8 KB, two shots) ----
        const _Float16* bsrc0 = Bw + (size_t)(n0 + ar) * K + (k0 + kq * 8);
        const _Float16* bsrc1 = Bw + (size_t)(n0 + 64 + ar) * K + (k0 + kq * 8);
        async_copy16((char*)Bs + (wid << 10), bsrc0);
        async_copy16((char*)Bs + 4096 + (wid << 10), bsrc1);

        __syncthreads();  // drains vmcnt (global_load_lds) before LDS reads

        half8 af[2], bf[4];
#pragma unroll
        for (int mi = 0; mi < 2; ++mi)
            af[mi] = *(const half8*)&As[(wm * 32 + mi * 16 + lcol) * 32 + quad * 8];
#pragma unroll
        for (int ni = 0; ni < 4; ++ni)
            bf[ni] = *(const half8*)&Bs[(wn * 64 + ni * 16 + lcol) * 32 + quad * 8];

#pragma unroll
        for (int mi = 0; mi < 2; ++mi)
#pragma unroll
            for (int ni = 0; ni < 4; ++ni)
                acc[mi][ni] = __builtin_amdgcn_mfma_f32_16x16x32_f16(
                    af[mi], bf[ni], acc[mi][ni], 0, 0, 0);

        __syncthreads();  // all LDS reads done before next overwrite
    }

    // Epilogue: C/D layout col=lane&15, row=quad*4+reg (dtype-independent).
#pragma unroll
    for (int mi = 0; mi < 2; ++mi) {
#pragma unroll
        for (int ni = 0; ni < 4; ++ni) {
            const int row = b0 + wm * 32 + mi * 16 + quad * 4;
            const int col = n0 + wn * 64 + ni * 16 + lcol;
            const float bv = bias ? bias[col] : 0.0f;
#pragma unroll
            for (int r = 0; r < 4; ++r)
                Out[(size_t)(row + r) * N + col] = acc[mi][ni][r] + bv;
        }
    }
}

// ---------------------------------------------------------------------------
// LSTM cell pointwise: gates P[b, {j, H+j, 2H+j, 3H+j}] -> c, h
// ---------------------------------------------------------------------------
__device__ __forceinline__ float fsig(float x)  { return 1.0f / (1.0f + __expf(-x)); }
__device__ __forceinline__ float ftanh(float x) { return 1.0f - 2.0f / (__expf(2.0f * x) + 1.0f); }

__global__ __launch_bounds__(256) void lstm_pointwise(
    const float* __restrict__ P, float* __restrict__ c, _Float16* __restrict__ h16)
{
    const int idx = blockIdx.x * 256 + threadIdx.x;  // 0 .. B*H
    if (idx >= B_ * HID_) return;
    const int b = idx >> 10;
    const int j = idx & (HID_ - 1);
    const float* Pb = P + (size_t)b * G4H_;
    const float iv = fsig(Pb[j]);
    const float fv = fsig(Pb[HID_ + j]);
    const float gv = ftanh(Pb[2 * HID_ + j]);
    const float ov = fsig(Pb[3 * HID_ + j]);
    const float cn = fv * c[idx] + iv * gv;
    c[idx] = cn;
    h16[idx] = (_Float16)(ov * ftanh(cn));
}

// ---------------------------------------------------------------------------
extern "C" void kernel_launch(void* const* d_in, const int* in_sizes, int n_in,
                              void* d_out, int out_size, void* d_ws, size_t ws_size,
                              hipStream_t stream)
{
    const int*   m     = (const int*)d_in[0];
    const float* emb   = (const float*)d_in[1];
    const float* W_ih  = (const float*)d_in[2];
    const float* W_hh  = (const float*)d_in[3];
    const float* b_ih  = (const float*)d_in[4];
    const float* b_hh  = (const float*)d_in[5];
    const float* W_out = (const float*)d_in[6];
    const float* b_out = (const float*)d_in[7];
    float* out = (float*)d_out;

    // Workspace layout (256B aligned), ~37 MB total.
    char* w = (char*)d_ws;
    size_t off = 0;
    auto alloc = [&](size_t bytes) {
        char* p = w + off;
        off = (off + bytes + 255) & ~(size_t)255;
        return p;
    };
    _Float16* emb16  = (_Float16*)alloc((size_t)VOCAB_ * EMB_ * 2);
    _Float16* Wc16   = (_Float16*)alloc((size_t)G4H_ * KCAT_ * 2);
    _Float16* Wout16 = (_Float16*)alloc((size_t)NIMG_ * HID_ * 2);
    float*    bias   = (float*)   alloc((size_t)G4H_ * 4);
    _Float16* h16    = (_Float16*)alloc((size_t)B_ * HID_ * 2);
    float*    cbuf   = (float*)   alloc((size_t)B_ * HID_ * 4);
    float*    Pbuf   = (float*)   alloc((size_t)B_ * G4H_ * 4);

    // 1) convert weights / init state
    {
        const long long total = (long long)VOCAB_ * EMB_ + (long long)G4H_ * KCAT_ +
                                (long long)NIMG_ * HID_ + G4H_ + 2LL * B_ * HID_;
        const int blocks = (int)((total + 255) / 256);
        convert_kernel<<<blocks, 256, 0, stream>>>(emb, W_ih, W_hh, b_ih, b_hh, W_out,
                                                   emb16, Wc16, Wout16, bias, cbuf, h16);
    }

    // 2) 64 recurrent steps: gates GEMM (gathered x_t ++ h) then pointwise cell
    for (int t = 0; t < T_; ++t) {
        gemm_f16<true><<<dim3(B_ / 64, G4H_ / 128), 256, 0, stream>>>(
            emb16, m + t, T_, h16, Wc16, bias, Pbuf, G4H_, KCAT_);
        lstm_pointwise<<<(B_ * HID_) / 256, 256, 0, stream>>>(Pbuf, cbuf, h16);
    }

    // 3) output projection: out = h @ W_out^T + b_out
    gemm_f16<false><<<dim3(B_ / 64, NIMG_ / 128), 256, 0, stream>>>(
        h16, nullptr, 0, nullptr, Wout16, b_out, out, NIMG_, HID_);
}

// Round 2
// 1865.940 us; speedup vs baseline: 1.2020x; 1.2020x over previous
//
#include <hip/hip_runtime.h>
#include <cstdint>

#define B_    512
#define T_    64
#define VOCAB_ 10000
#define EMB_  512
#define HID_  1024
#define G4H_  4096      // 4*HID
#define KCAT_ 1536      // EMB + HID
#define NIMG_ 2048

typedef _Float16 half8 __attribute__((ext_vector_type(8)));
typedef float floatx4 __attribute__((ext_vector_type(4)));

// Async global->LDS, 16B per lane. LDS dest = wave-uniform base (HW adds
// lane*16). Per-lane SOURCE address is free (gather OK).
__device__ __forceinline__ void async_copy16(void* lds_uniform, const void* gsrc) {
    __builtin_amdgcn_global_load_lds(
        (__attribute__((address_space(1))) void*)(uintptr_t)gsrc,
        (__attribute__((address_space(3))) void*)(uint32_t)(uintptr_t)lds_uniform,
        16, 0, 0);
}

__device__ __forceinline__ float fsig(float x)  { return 1.0f / (1.0f + __expf(-x)); }
__device__ __forceinline__ float ftanh(float x) { return 1.0f - 2.0f / (__expf(2.0f * x) + 1.0f); }

// Gate-interleaved weight-row permutation:
//   n_perm = jblk*64 + gate*16 + jlo   <->   n_orig = gate*HID + (jblk*16 + jlo)
// so a 64-column block tile holds all 4 gates for 16 consecutive j's, and
// lane lcol owns one j with gates in acc[0..3] (fused LSTM epilogue).

// ---------------------------------------------------------------------------
// One-time conversions: emb->f16, Wc16 = permuted [W_ih|W_hh] (N_perm x KCAT),
// Wout16, biasp = permuted (b_ih+b_hh), c=0, hA=0, tokperm[t*B+b]=m[b][t].
// ---------------------------------------------------------------------------
__global__ __launch_bounds__(256) void convert_kernel(
    const int* __restrict__ m, const float* __restrict__ emb,
    const float* __restrict__ W_ih, const float* __restrict__ W_hh,
    const float* __restrict__ b_ih, const float* __restrict__ b_hh,
    const float* __restrict__ W_out,
    _Float16* __restrict__ emb16, _Float16* __restrict__ Wc16,
    _Float16* __restrict__ Wout16, float* __restrict__ biasp,
    float* __restrict__ c, _Float16* __restrict__ hA, int* __restrict__ tokperm)
{
    const long long EMB_N = (long long)VOCAB_ * EMB_;
    const long long WC_N  = (long long)G4H_ * KCAT_;
    const long long WO_N  = (long long)NIMG_ * HID_;
    const long long BI_N  = G4H_;
    const long long ST_N  = (long long)B_ * HID_;
    const long long TK_N  = (long long)B_ * T_;

    long long i = (long long)blockIdx.x * 256 + threadIdx.x;
    if (i < EMB_N) { emb16[i] = (_Float16)emb[i]; return; }
    i -= EMB_N;
    if (i < WC_N) {
        int n_perm = (int)(i / KCAT_);
        int k      = (int)(i % KCAT_);
        int gate = (n_perm >> 4) & 3;
        int j    = (n_perm >> 6) * 16 + (n_perm & 15);
        int n_orig = gate * HID_ + j;
        float v = (k < EMB_) ? W_ih[(size_t)n_orig * EMB_ + k]
                             : W_hh[(size_t)n_orig * HID_ + (k - EMB_)];
        Wc16[i] = (_Float16)v;
        return;
    }
    i -= WC_N;
    if (i < WO_N) { Wout16[i] = (_Float16)W_out[i]; return; }
    i -= WO_N;
    if (i < BI_N) {
        int n_perm = (int)i;
        int gate = (n_perm >> 4) & 3;
        int j    = (n_perm >> 6) * 16 + (n_perm & 15);
        int n_orig = gate * HID_ + j;
        biasp[i] = b_ih[n_orig] + b_hh[n_orig];
        return;
    }
    i -= BI_N;
    if (i < ST_N) { c[i] = 0.0f; return; }
    i -= ST_N;
    if (i < ST_N) { hA[i] = (_Float16)0.0f; return; }
    i -= ST_N;
    if (i < TK_N) {
        int t = (int)(i / B_), b = (int)(i % B_);
        tokperm[i] = m[(size_t)b * T_ + t];
    }
}

// ---------------------------------------------------------------------------
// Xp precompute GEMM: Xp[t*B+b][n_perm] = emb16[tok] @ W_ih_perm^T + biasp
// 128x128 tile (m97-style), 256 thr = 4 waves 2x2, BK=32, K=512 (16 iters).
// ---------------------------------------------------------------------------
__global__ __launch_bounds__(256) void gemm_xproj(
    const _Float16* __restrict__ emb16, const int* __restrict__ tokperm,
    const _Float16* __restrict__ Wc16, const float* __restrict__ biasp,
    _Float16* __restrict__ Xp)
{
    __shared__ __align__(16) _Float16 As[128 * 32];
    __shared__ __align__(16) _Float16 Bs[128 * 32];
    __shared__ int tok_s[128];

    const int tid  = threadIdx.x;
    const int wid  = tid >> 6;
    const int lane = tid & 63;
    const int lcol = lane & 15;
    const int quad = lane >> 4;
    const int wm   = wid >> 1;
    const int wn   = wid & 1;

    const int r0 = blockIdx.x * 128;
    const int n0 = blockIdx.y * 128;

    if (tid < 128) tok_s[tid] = tokperm[r0 + tid];
    __syncthreads();

    floatx4 acc[4][4];
#pragma unroll
    for (int i = 0; i < 4; ++i)
#pragma unroll
        for (int j = 0; j < 4; ++j) acc[i][j] = (floatx4){0.f, 0.f, 0.f, 0.f};

    const int ar = tid >> 2;  // 0..63
    const int kq = tid & 3;

    for (int k0 = 0; k0 < EMB_; k0 += 32) {
        // A tile 128x32: two 4KB shots
        async_copy16((char*)As + (wid << 10),
                     emb16 + (size_t)tok_s[ar] * EMB_ + (k0 + kq * 8));
        async_copy16((char*)As + 4096 + (wid << 10),
                     emb16 + (size_t)tok_s[64 + ar] * EMB_ + (k0 + kq * 8));
        // B tile 128x32: two 4KB shots (Wc16 row stride KCAT)
        async_copy16((char*)Bs + (wid << 10),
                     Wc16 + (size_t)(n0 + ar) * KCAT_ + (k0 + kq * 8));
        async_copy16((char*)Bs + 4096 + (wid << 10),
                     Wc16 + (size_t)(n0 + 64 + ar) * KCAT_ + (k0 + kq * 8));
        __syncthreads();

        half8 af[4], bf[4];
#pragma unroll
        for (int mi = 0; mi < 4; ++mi)
            af[mi] = *(const half8*)&As[(wm * 64 + mi * 16 + lcol) * 32 + quad * 8];
#pragma unroll
        for (int ni = 0; ni < 4; ++ni)
            bf[ni] = *(const half8*)&Bs[(wn * 64 + ni * 16 + lcol) * 32 + quad * 8];
#pragma unroll
        for (int mi = 0; mi < 4; ++mi)
#pragma unroll
            for (int ni = 0; ni < 4; ++ni)
                acc[mi][ni] = __builtin_amdgcn_mfma_f32_16x16x32_f16(
                    af[mi], bf[ni], acc[mi][ni], 0, 0, 0);
        __syncthreads();
    }

#pragma unroll
    for (int mi = 0; mi < 4; ++mi) {
#pragma unroll
        for (int ni = 0; ni < 4; ++ni) {
            const int row = r0 + wm * 64 + mi * 16 + quad * 4;
            const int col = n0 + wn * 64 + ni * 16 + lcol;
            const float bv = biasp[col];
#pragma unroll
            for (int r = 0; r < 4; ++r)
                Xp[(size_t)(row + r) * G4H_ + col] = (_Float16)(acc[mi][ni][r] + bv);
        }
    }
}

// ---------------------------------------------------------------------------
// Recurrent step, fused LSTM epilogue. Tile 64(M) x 64(N_perm), 4 waves
// stacked in M (each 16 rows x 64 cols, acc[ni=gate][4]). Grid (8,64)=512
// blocks -> 2 blocks/CU for latency overlap.
// XP=true : acc init from Xp (K = 512..1536, W_hh part only)
// XP=false: acc init = biasp, x gathered from emb16 (K = 0..1536)
// ---------------------------------------------------------------------------
template <bool XP>
__global__ __launch_bounds__(256) void step_kernel(
    const _Float16* __restrict__ emb16, const int* __restrict__ m, int t,
    const _Float16* __restrict__ Xp, const _Float16* __restrict__ h_prev,
    const _Float16* __restrict__ Wc16, const float* __restrict__ biasp,
    float* __restrict__ c, _Float16* __restrict__ h_next)
{
    __shared__ __align__(16) _Float16 As[64 * 32];
    __shared__ __align__(16) _Float16 Bs[64 * 32];
    __shared__ int tok_s[64];

    const int tid  = threadIdx.x;
    const int wid  = tid >> 6;   // wave = M-stripe 0..3
    const int lane = tid & 63;
    const int lcol = lane & 15;
    const int quad = lane >> 4;

    const int b0 = blockIdx.x * 64;
    const int n0 = blockIdx.y * 64;   // permuted col base; j = blockIdx.y*16 + lcol

    if (!XP) {
        if (tid < 64) tok_s[tid] = m[(size_t)(b0 + tid) * T_ + t];
        __syncthreads();
    }

    const int rowbase = b0 + wid * 16 + quad * 4;

    floatx4 acc[4];
#pragma unroll
    for (int ni = 0; ni < 4; ++ni) {
        if (XP) {
            const _Float16* xp = Xp + (size_t)(t * B_ + rowbase) * G4H_ + (n0 + ni * 16 + lcol);
#pragma unroll
            for (int r = 0; r < 4; ++r) acc[ni][r] = (float)xp[(size_t)r * G4H_];
        } else {
            const float bv = biasp[n0 + ni * 16 + lcol];
#pragma unroll
            for (int r = 0; r < 4; ++r) acc[ni][r] = bv;
        }
    }

    const int ar = tid >> 2;  // 0..63
    const int kq = tid & 3;

    const int kstart = XP ? EMB_ : 0;
    for (int k0 = kstart; k0 < KCAT_; k0 += 32) {
        const _Float16* asrc;
        if (!XP && k0 < EMB_)
            asrc = emb16 + (size_t)tok_s[ar] * EMB_ + (k0 + kq * 8);
        else
            asrc = h_prev + (size_t)(b0 + ar) * HID_ + (k0 - EMB_ + kq * 8);
        async_copy16((char*)As + (wid << 10), asrc);
        async_copy16((char*)Bs + (wid << 10),
                     Wc16 + (size_t)(n0 + ar) * KCAT_ + (k0 + kq * 8));
        __syncthreads();

        half8 af = *(const half8*)&As[(wid * 16 + lcol) * 32 + quad * 8];
        half8 bf[4];
#pragma unroll
        for (int ni = 0; ni < 4; ++ni)
            bf[ni] = *(const half8*)&Bs[(ni * 16 + lcol) * 32 + quad * 8];
#pragma unroll
        for (int ni = 0; ni < 4; ++ni)
            acc[ni] = __builtin_amdgcn_mfma_f32_16x16x32_f16(af, bf[ni], acc[ni], 0, 0, 0);
        __syncthreads();
    }

    // Fused LSTM cell: lane owns j = blockIdx.y*16 + lcol, rows rowbase+r.
    const int j = blockIdx.y * 16 + lcol;
#pragma unroll
    for (int r = 0; r < 4; ++r) {
        const size_t idx = (size_t)(rowbase + r) * HID_ + j;
        const float iv = fsig(acc[0][r]);
        const float fv = fsig(acc[1][r]);
        const float gv = ftanh(acc[2][r]);
        const float ov = fsig(acc[3][r]);
        const float cn = fv * c[idx] + iv * gv;
        c[idx] = cn;
        h_next[idx] = (_Float16)(ov * ftanh(cn));
    }
}

// ---------------------------------------------------------------------------
// Final projection GEMM (unpermuted): Out = h @ Wout16^T + b_out
// 64x128 tile, 4 waves 2x2.
// ---------------------------------------------------------------------------
__global__ __launch_bounds__(256) void gemm_out(
    const _Float16* __restrict__ A, const _Float16* __restrict__ Bw,
    const float* __restrict__ bias, float* __restrict__ Out, int N, int K)
{
    __shared__ __align__(16) _Float16 As[64 * 32];
    __shared__ __align__(16) _Float16 Bs[128 * 32];

    const int tid  = threadIdx.x;
    const int wid  = tid >> 6;
    const int lane = tid & 63;
    const int lcol = lane & 15;
    const int quad = lane >> 4;
    const int wm   = wid >> 1;
    const int wn   = wid & 1;

    const int b0 = blockIdx.x * 64;
    const int n0 = blockIdx.y * 128;

    floatx4 acc[2][4];
#pragma unroll
    for (int i = 0; i < 2; ++i)
#pragma unroll
        for (int j = 0; j < 4; ++j) acc[i][j] = (floatx4){0.f, 0.f, 0.f, 0.f};

    const int ar = tid >> 2;
    const int kq = tid & 3;

    for (int k0 = 0; k0 < K; k0 += 32) {
        async_copy16((char*)As + (wid << 10), A + (size_t)(b0 + ar) * K + (k0 + kq * 8));
        async_copy16((char*)Bs + (wid << 10), Bw + (size_t)(n0 + ar) * K + (k0 + kq * 8));
        async_copy16((char*)Bs + 4096 + (wid << 10),
                     Bw + (size_t)(n0 + 64 + ar) * K + (k0 + kq * 8));
        __syncthreads();

        half8 af[2], bf[4];
#pragma unroll
        for (int mi = 0; mi < 2; ++mi)
            af[mi] = *(const half8*)&As[(wm * 32 + mi * 16 + lcol) * 32 + quad * 8];
#pragma unroll
        for (int ni = 0; ni < 4; ++ni)
            bf[ni] = *(const half8*)&Bs[(wn * 64 + ni * 16 + lcol) * 32 + quad * 8];
#pragma unroll
        for (int mi = 0; mi < 2; ++mi)
#pragma unroll
            for (int ni = 0; ni < 4; ++ni)
                acc[mi][ni] = __builtin_amdgcn_mfma_f32_16x16x32_f16(
                    af[mi], bf[ni], acc[mi][ni], 0, 0, 0);
        __syncthreads();
    }

#pragma unroll
    for (int mi = 0; mi < 2; ++mi) {
#pragma unroll
        for (int ni = 0; ni < 4; ++ni) {
            const int row = b0 + wm * 32 + mi * 16 + quad * 4;
            const int col = n0 + wn * 64 + ni * 16 + lcol;
            const float bv = bias[col];
#pragma unroll
            for (int r = 0; r < 4; ++r)
                Out[(size_t)(row + r) * N + col] = acc[mi][ni][r] + bv;
        }
    }
}

// ---------------------------------------------------------------------------
extern "C" void kernel_launch(void* const* d_in, const int* in_sizes, int n_in,
                              void* d_out, int out_size, void* d_ws, size_t ws_size,
                              hipStream_t stream)
{
    const int*   m     = (const int*)d_in[0];
    const float* emb   = (const float*)d_in[1];
    const float* W_ih  = (const float*)d_in[2];
    const float* W_hh  = (const float*)d_in[3];
    const float* b_ih  = (const float*)d_in[4];
    const float* b_hh  = (const float*)d_in[5];
    const float* W_out = (const float*)d_in[6];
    const float* b_out = (const float*)d_in[7];
    float* out = (float*)d_out;

    char* w = (char*)d_ws;
    size_t off = 0;
    auto alloc = [&](size_t bytes) {
        char* p = w + off;
        off = (off + bytes + 255) & ~(size_t)255;
        return p;
    };
    _Float16* emb16   = (_Float16*)alloc((size_t)VOCAB_ * EMB_ * 2);
    _Float16* Wc16    = (_Float16*)alloc((size_t)G4H_ * KCAT_ * 2);
    _Float16* Wout16  = (_Float16*)alloc((size_t)NIMG_ * HID_ * 2);
    float*    biasp   = (float*)   alloc((size_t)G4H_ * 4);
    _Float16* hA      = (_Float16*)alloc((size_t)B_ * HID_ * 2);
    _Float16* hB      = (_Float16*)alloc((size_t)B_ * HID_ * 2);
    float*    cbuf    = (float*)   alloc((size_t)B_ * HID_ * 4);
    int*      tokperm = (int*)     alloc((size_t)B_ * T_ * 4);
    size_t base_need = off;
    _Float16* Xp      = (_Float16*)alloc((size_t)B_ * T_ * G4H_ * 2);  // 268 MB
    const bool useXP = (ws_size >= off);
    (void)base_need;

    // 1) convert / permute / init
    {
        const long long total = (long long)VOCAB_ * EMB_ + (long long)G4H_ * KCAT_ +
                                (long long)NIMG_ * HID_ + G4H_ +
                                2LL * B_ * HID_ + (long long)B_ * T_;
        convert_kernel<<<(int)((total + 255) / 256), 256, 0, stream>>>(
            m, emb, W_ih, W_hh, b_ih, b_hh, W_out,
            emb16, Wc16, Wout16, biasp, cbuf, hA, tokperm);
    }

    // 2) Xp = x @ W_ih^T + bias for ALL timesteps (one parallel GEMM)
    if (useXP) {
        gemm_xproj<<<dim3(B_ * T_ / 128, G4H_ / 128), 256, 0, stream>>>(
            emb16, tokperm, Wc16, biasp, Xp);
    }

    // 3) 64 recurrent steps, fused gates GEMM + LSTM cell. h ping-pongs.
    for (int t = 0; t < T_; ++t) {
        const _Float16* hp = (t & 1) ? hB : hA;
        _Float16*       hn = (t & 1) ? hA : hB;
        if (useXP)
            step_kernel<true><<<dim3(B_ / 64, G4H_ / 64), 256, 0, stream>>>(
                emb16, m, t, Xp, hp, Wc16, biasp, cbuf, hn);
        else
            step_kernel<false><<<dim3(B_ / 64, G4H_ / 64), 256, 0, stream>>>(
                emb16, m, t, nullptr, hp, Wc16, biasp, cbuf, hn);
    }

    // 4) out = h @ W_out^T + b_out   (T_ even -> final h is in hA)
    gemm_out<<<dim3(B_ / 64, NIMG_ / 128), 256, 0, stream>>>(
        hA, Wout16, b_out, out, NIMG_, HID_);
}